// Round 24
// baseline (147.767 us; speedup 1.0000x reference)
//
#include <hip/hip_runtime.h>

#define BB 8
#define HH 48
#define WW 48
#define DD 64
#define NSEQ (HH*WW)   // 2304

typedef unsigned short u16;
typedef unsigned long long u64;
typedef __attribute__((ext_vector_type(8))) short short8;
typedef __attribute__((ext_vector_type(4))) float f32x4;

__device__ __forceinline__ float bf2f(u16 u){ return __uint_as_float(((unsigned)u)<<16); }
__device__ __forceinline__ u16 f2bf(float f){
  unsigned u = __float_as_uint(f);
  return (u16)((u + 0x7fffu + ((u>>16)&1u)) >> 16);   // RNE
}
__device__ __forceinline__ f32x4 mfma16(short8 a, short8 b, f32x4 c){
  return __builtin_amdgcn_mfma_f32_16x16x32_bf16(a, b, c, 0, 0, 0);
}

// ------- fused weight transpose -> MFMA-FRAGMENT-PACKED bf16 --------------------------
// dst layout per tensor: [kpos][cot][ks][lane][8], elem = W[ci=ks*32+(lane>>4)*8+j][co=cot*16+(lane&15)]
struct WtSrcs { const float* src[7]; };
__global__ __launch_bounds__(256) void wtrans_all(WtSrcs s, u16* __restrict__ dst){
  int i = blockIdx.x*256 + threadIdx.x;       // total 663552
  if(i >= 663552) return;
  const float* sp; int local, CI, CO;
  if(i < 184320){ int seg = i/36864; local = i - seg*36864; sp = s.src[seg]; CI = 64; CO = 64; }
  else if(i < 331776){ local = i - 184320; sp = s.src[5]; CI = 128; CO = 128; }
  else { local = i - 331776; sp = s.src[6]; CI = 192; CO = 192; }
  int j    = local & 7;
  int lane = (local >> 3) & 63;
  int blk  = local >> 9;                      // (kpos*(CO/16)+cot)*(CI/32)+ks
  int nks  = CI/32;
  int ks   = blk % nks;
  int rem  = blk / nks;
  int cot  = rem % (CO/16);
  int kpos = rem / (CO/16);
  int ci = ks*32 + (lane>>4)*8 + j;
  int co = cot*16 + (lane&15);
  dst[i] = f2bf(sp[((size_t)kpos*CI + ci)*CO + co]);
}

// ----- merged multi-conv 64->64 (MFMA), PIXEL-TILED: z = stream*3 + 16-px tile --------
struct ConvPtrs {
  const u16*   W[3];     // packed bf16
  const float* bias[3];  // f32
  u16*         out[3];   // bf16
  int          vt[3];    // 1 -> write transposed [b][co][seq]
  int          nc;       // active weight sets
};

__global__ __launch_bounds__(256) void conv64_mfma(
    const float* __restrict__ in0, const float* __restrict__ in1,
    ConvPtrs p0, ConvPtrs p1){
  __shared__ u16 lds[3][18][72];
  const int sidx = blockIdx.z / 3, pt = blockIdx.z % 3;
  const float* in = sidx ? in1 : in0;
  ConvPtrs p = sidx ? p1 : p0;
  const int b = blockIdx.x / HH, y = blockIdx.x % HH;
  const int tid  = threadIdx.x;
  const int wave = tid >> 6, lane = tid & 63, g = lane >> 4, col = lane & 15;
  const short8 Z8 = {0,0,0,0,0,0,0,0};

  for(int ky=0; ky<3; ky++){
    int ys = y + ky - 1;
    const int NCH = 18*64/8;                   // 144 chunks
    if(ys < 0 || ys >= HH){
      for(int c8 = tid; c8 < NCH; c8 += 256){
        int px = c8 >> 3, cb = (c8 & 7)*8;
        *(short8*)&lds[ky][px][cb] = Z8;
      }
    } else {
      const float* rowp = in + (size_t)(b*HH + ys)*WW*64;
      for(int c8 = tid; c8 < NCH; c8 += 256){
        int px = c8 >> 3, cb = (c8 & 7)*8;
        int x = pt*16 + px - 1;
        short8 v;
        if(x < 0 || x >= WW) v = Z8;
        else {
          #pragma unroll
          for(int j=0;j<8;j++) v[j] = (short)f2bf(rowp[x*64 + cb + j]);
        }
        *(short8*)&lds[ky][px][cb] = v;
      }
    }
  }
  __syncthreads();

  const f32x4 zf = {0.f,0.f,0.f,0.f};
  f32x4 acc[3];
  #pragma unroll
  for(int c=0; c<3; c++) acc[c] = zf;

  const int nc = p.nc;
  #pragma unroll
  for(int ky=0; ky<3; ky++)
  #pragma unroll
  for(int kx=0; kx<3; kx++)
  #pragma unroll
  for(int ks=0; ks<2; ks++){
    short8 a = *(const short8*)&lds[ky][col + kx][ks*32 + g*8];
    #pragma unroll
    for(int c=0; c<3; c++){
      if(c < nc){
        const u16* wp = p.W[c] + ((((ky*3+kx)*4 + wave)*2 + ks)<<9) + lane*8;
        short8 bfr = *(const short8*)wp;
        acc[c] = mfma16(a, bfr, acc[c]);
      }
    }
  }

  #pragma unroll
  for(int c=0; c<3; c++){
    if(c >= nc) continue;
    int co = wave*16 + col;
    float bs = p.bias[c][co];
    if(p.vt[c]){
      u16* op = p.out[c] + ((size_t)(b*64 + co))*NSEQ + (size_t)y*WW;
      int px = pt*16 + g*4;
      u64 pk =  (u64)f2bf(acc[c][0] + bs)
             | ((u64)f2bf(acc[c][1] + bs) << 16)
             | ((u64)f2bf(acc[c][2] + bs) << 32)
             | ((u64)f2bf(acc[c][3] + bs) << 48);
      *(u64*)&op[px] = pk;
    } else {
      u16* op = p.out[c] + ((size_t)(b*HH + y)*WW)*64 + co;
      #pragma unroll
      for(int r=0; r<4; r++){
        int px = pt*16 + g*4 + r;
        op[(size_t)px*64] = f2bf(acc[c][r] + bs);
      }
    }
  }
}

// ------- split-K single-stream flash attention: QBLK=64, 4 strip-waves ---------------
// FIXED-MAX softmax (m == 0): P = exp(S). Row-sums l via MFMA against a ones-tile.
__global__ __launch_bounds__(256) void attn2_mfma(
    const u16* __restrict__ q,
    const u16* __restrict__ kh, const u16* __restrict__ vhT,
    const u16* __restrict__ km2, const u16* __restrict__ vmT,
    u16* __restrict__ po, u16* __restrict__ pox, float2* __restrict__ ml){
  __shared__ u16 Ks [64*64];    // [key][d] swizzled
  __shared__ u16 Vts[80*64];    // [d][key] swizzled; rows 64..79 = ones
  __shared__ u16 Ps [64*64];    // [qrow][key] swizzled (wave-private strips)
  const int qt = blockIdx.x, b = blockIdx.y;
  const int s = blockIdx.z / 3, ch = blockIdx.z % 3;
  const int tid = threadIdx.x, wave = tid>>6, lane = tid&63;
  const int g = lane>>4, col = lane&15;
  const int strip = wave;
  const size_t NP = (size_t)BB*NSEQ*DD;

  const u16* kk = s ? km2 : kh;
  const u16* vT = s ? vmT : vhT;

  const u16* qp = q + ((size_t)(b*NSEQ + qt*64 + strip*16 + col))*DD;
  short8 aq0 = *(const short8*)&qp[g*8];
  short8 aq1 = *(const short8*)&qp[32 + g*8];

  const int r0a = tid>>3, gr = tid&7, cb0 = gr*8;
  const int r0b = r0a + 32;
  const int stA = r0a*64 + ((gr ^ (r0a&7))<<3);
  const int stB = stA + 32*64;
  const size_t tb  = (size_t)(b*NSEQ)*DD;
  const size_t tbT = (size_t)(b*64)*NSEQ;

  const int cg0 = ((g     ^ (col&7))<<3);
  const int cg1 = (((4+g) ^ (col&7))<<3);

  for(int idx = tid; idx < 16*64; idx += 256) Vts[64*64 + idx] = 0x3F80;  // bf16 1.0

  short8 paK0,paK1,paV0,paV1;
  short8 pbK0,pbK1,pbV0,pbV1;

  const f32x4 zf = {0.f,0.f,0.f,0.f};
  f32x4 o[4];
  #pragma unroll
  for(int nt=0; nt<4; nt++) o[nt] = zf;
  f32x4 ol = zf;                               // l accumulator

#define BAR() { __builtin_amdgcn_s_barrier(); __builtin_amdgcn_sched_barrier(0); }
#define LWAIT() { asm volatile("s_waitcnt lgkmcnt(0)" ::: "memory"); __builtin_amdgcn_sched_barrier(0); }

#define LOADSET(K0,K1,V0,V1, kt_) {                                        \
    size_t offK0 = tb + (size_t)(kt_)*64*DD + (size_t)r0a*DD + cb0;        \
    size_t offK1 = tb + (size_t)(kt_)*64*DD + (size_t)r0b*DD + cb0;        \
    size_t offV0 = tbT + (size_t)r0a*NSEQ + (size_t)(kt_)*64 + cb0;        \
    size_t offV1 = tbT + (size_t)r0b*NSEQ + (size_t)(kt_)*64 + cb0;        \
    K0 = *(const short8*)&kk[offK0];  K1 = *(const short8*)&kk[offK1];     \
    V0 = *(const short8*)&vT[offV0];  V1 = *(const short8*)&vT[offV1];     \
  }
#define STORESET(K0,K1,V0,V1) {                                            \
    *(short8*)&Ks [stA] = K0;   *(short8*)&Ks [stB] = K1;                  \
    *(short8*)&Vts[stA] = V0;   *(short8*)&Vts[stB] = V1;                  \
  }
#define COMPUTE() {                                                 \
    __builtin_amdgcn_s_setprio(1);                                  \
    f32x4 sv[4];                                                    \
    _Pragma("unroll")                                               \
    for(int nt=0; nt<4; nt++){                                      \
      sv[nt] = zf;                                                  \
      int rowb = (nt*16 + col)*64;                                  \
      short8 bk0 = *(const short8*)&Ks[rowb + cg0];                 \
      sv[nt] = mfma16(aq0, bk0, sv[nt]);                            \
      short8 bk1 = *(const short8*)&Ks[rowb + cg1];                 \
      sv[nt] = mfma16(aq1, bk1, sv[nt]);                            \
    }                                                               \
    _Pragma("unroll")                                               \
    for(int r=0; r<4; r++){                                         \
      int prow = strip*16 + g*4 + r;                                \
      int pbase = prow*64;                                          \
      _Pragma("unroll")                                             \
      for(int nt=0; nt<4; nt++)                                     \
        Ps[pbase + (((nt*2 + (col>>3)) ^ (prow&7))<<3) + (col&7)] = f2bf(__expf(sv[nt][r])); \
    }                                                               \
    int prowr = strip*16 + col;                                     \
    _Pragma("unroll")                                               \
    for(int ks=0; ks<2; ks++){                                      \
      short8 ap = *(const short8*)&Ps[prowr*64 + (ks ? cg1 : cg0)]; \
      _Pragma("unroll")                                             \
      for(int nt=0; nt<4; nt++){                                    \
        short8 bv = *(const short8*)&Vts[(nt*16 + col)*64 + (ks ? cg1 : cg0)]; \
        o[nt] = mfma16(ap, bv, o[nt]);                              \
      }                                                             \
      short8 b1 = *(const short8*)&Vts[(64 + col)*64 + (ks ? cg1 : cg0)]; \
      ol = mfma16(ap, b1, ol);                                      \
    }                                                               \
    __builtin_amdgcn_s_setprio(0);                                  \
  }

  const int kt0 = ch*12;                     // 12 tiles of 64 keys per chunk
  LOADSET(paK0,paK1,paV0,paV1, kt0);
  for(int kt = kt0; kt < kt0+12; kt += 2){
    LOADSET(pbK0,pbK1,pbV0,pbV1, kt+1);
    BAR();
    STORESET(paK0,paK1,paV0,paV1);
    LWAIT();
    BAR();
    COMPUTE();
    if(kt+2 < kt0+12) LOADSET(paK0,paK1,paV0,paV1, kt+2);
    BAR();
    STORESET(pbK0,pbK1,pbV0,pbV1);
    LWAIT();
    BAR();
    COMPUTE();
  }

  const int ridx = s*3 + ch;
  u16* rbase = (ridx < 4) ? (po + (size_t)ridx*NP) : (pox + (size_t)(ridx-4)*NP);
  u16* pb = rbase + ((size_t)(b*NSEQ + qt*64 + strip*16))*DD;
  #pragma unroll
  for(int nt=0; nt<4; nt++)
    #pragma unroll
    for(int r=0; r<4; r++)
      pb[(g*4 + r)*DD + nt*16 + col] = f2bf(o[nt][r]);
  if(col == 0){
    #pragma unroll
    for(int r=0; r<4; r++){
      int qrow = qt*64 + strip*16 + g*4 + r;
      float2 v; v.x = 0.f; v.y = ol[r];
      ml[(size_t)ridx*BB*NSEQ + (size_t)b*NSEQ + qrow] = v;
    }
  }
#undef LOADSET
#undef STORESET
#undef COMPUTE
#undef BAR
#undef LWAIT
}

// ------- combine 3 KV-chunks per stream (all m=0): z_h -> po 0, z_m -> po 1 -----------
__global__ __launch_bounds__(256) void attn_combine(u16* po, const u16* __restrict__ pox,
                                                    const float2* __restrict__ ml){
  const size_t NP = (size_t)BB*NSEQ*DD;
  const size_t RORD = (size_t)BB*NSEQ;
  for(size_t e = (size_t)blockIdx.x*256 + threadIdx.x; e < NP; e += (size_t)gridDim.x*256){
    size_t row = e / DD;
    float lh = ml[row].y + ml[RORD + row].y + ml[2*RORD + row].y;
    float lm = ml[3*RORD + row].y + ml[4*RORD + row].y + ml[5*RORD + row].y;
    float oh = bf2f(po[e]) + bf2f(po[NP + e]) + bf2f(po[2*NP + e]);
    float om = bf2f(po[3*NP + e]) + bf2f(pox[e]) + bf2f(pox[NP + e]);
    po[e]      = f2bf(oh/lh);   // z_h
    po[NP + e] = f2bf(om/lm);   // z_m (overwrites h-c1; this thread read it already)
  }
}

// -------- big conv (MFMA), PIXEL-TILED + packed weights: blockIdx.z = 16-px tile ------
template<int CIN, int COUT, int SPLIT, bool GATE, bool IN1F>
__global__ __launch_bounds__(256) void bigconv_mfma(
    const u16* __restrict__ in0, const u16* __restrict__ in1b, const float* __restrict__ in1f,
    const u16* __restrict__ Wt, const float* __restrict__ bias,
    void* __restrict__ out0v, void* __restrict__ out1v, const float* __restrict__ mem){
  constexpr int SP  = CIN + 8;
  constexpr int NTW = COUT/64;
  __shared__ u16 lds[3][18][SP];
  const int b = blockIdx.x / HH, y = blockIdx.x % HH;
  const int pt = blockIdx.z;                 // pixel tile: global px0 = pt*16
  const int tid  = threadIdx.x;
  const int wave = tid >> 6, lane = tid & 63, g = lane >> 4, col = lane & 15;
  const short8 Z8 = {0,0,0,0,0,0,0,0};

  for(int ky=0; ky<3; ky++){
    int ys = y + ky - 1;
    const int NCH = 18*CIN/8;
    if(ys < 0 || ys >= HH){
      for(int c8 = tid; c8 < NCH; c8 += 256){
        int px = c8 / (CIN/8), cb = (c8 % (CIN/8))*8;
        *(short8*)&lds[ky][px][cb] = Z8;
      }
    } else {
      size_t base0 = (size_t)(b*HH + ys)*WW*SPLIT;
      size_t base1 = (size_t)(b*HH + ys)*WW*(CIN-SPLIT);
      for(int c8 = tid; c8 < NCH; c8 += 256){
        int px = c8 / (CIN/8), cb = (c8 % (CIN/8))*8;
        int x = pt*16 + px - 1;
        short8 val;
        if(x < 0 || x >= WW){
          val = Z8;
        } else if(cb < SPLIT){
          val = *(const short8*)&in0[base0 + (size_t)x*SPLIT + cb];
        } else if constexpr (IN1F){
          const float* sp = &in1f[base1 + (size_t)x*(CIN-SPLIT) + cb - SPLIT];
          #pragma unroll
          for(int j=0;j<8;j++) val[j] = (short)f2bf(sp[j]);
        } else {
          val = *(const short8*)&in1b[base1 + (size_t)x*(CIN-SPLIT) + cb - SPLIT];
        }
        *(short8*)&lds[ky][px][cb] = val;
      }
    }
  }
  __syncthreads();

  const f32x4 zf = {0.f,0.f,0.f,0.f};
  f32x4 acc[NTW];
  #pragma unroll
  for(int i=0; i<NTW; i++) acc[i] = zf;

  #pragma unroll
  for(int ky=0; ky<3; ky++)
  #pragma unroll
  for(int kx=0; kx<3; kx++)
  #pragma unroll
  for(int ks=0; ks<CIN/32; ks++){
    short8 a = *(const short8*)&lds[ky][col + kx][ks*32 + g*8];
    #pragma unroll
    for(int i=0; i<NTW; i++){
      const u16* wp = Wt + (((((ky*3+kx)*(COUT/16)) + (wave + 4*i))*(CIN/32) + ks)<<9) + lane*8;
      short8 bfr = *(const short8*)wp;
      acc[i] = mfma16(a, bfr, acc[i]);
    }
  }

  if constexpr (!GATE){
    u16* out0 = (u16*)out0v;
    #pragma unroll
    for(int i=0; i<NTW; i++){
      int co = (wave + 4*i)*16 + col;
      float bs = bias[co];
      u16* op = out0 + (size_t)(b*HH + y)*WW*COUT + co;
      #pragma unroll
      for(int r=0; r<4; r++){
        int px = pt*16 + g*4 + r;
        op[(size_t)px*COUT] = f2bf(acc[i][r] + bs);
      }
    }
  } else {
    float* oh = (float*)out0v;
    float* om = (float*)out1v;
    int c = wave*16 + col;
    float bo = bias[c], bg = bias[64+c], bgi = bias[128+c];
    #pragma unroll
    for(int r=0; r<4; r++){
      int px = pt*16 + g*4 + r;
      size_t idx = ((size_t)(b*HH + y)*WW + px)*64 + c;
      float mo = acc[0][r] + bo;
      float mg = acc[1][r] + bg;
      float gi = acc[2][r] + bgi;
      float mval = mem[idx];
      float si = 1.f/(1.f + __expf(-gi));
      float nm = (1.f - si)*mval + si*tanhf(mg);
      float nh = (1.f/(1.f + __expf(-mo)))*nm;
      oh[idx] = nh;
      om[idx] = nm;
    }
  }
}

// ---------------- launcher ----------------
extern "C" void kernel_launch(void* const* d_in, const int* in_sizes, int n_in,
                              void* d_out, int out_size, void* d_ws, size_t ws_size,
                              hipStream_t stream){
  (void)in_sizes; (void)n_in; (void)out_size; (void)ws_size;
  const float* h   = (const float*)d_in[0];
  const float* m   = (const float*)d_in[1];
  const float* Wq  = (const float*)d_in[2];  const float* bq  = (const float*)d_in[3];
  const float* Wk  = (const float*)d_in[4];  const float* bk  = (const float*)d_in[5];
  const float* Wk2 = (const float*)d_in[6];  const float* bk2 = (const float*)d_in[7];
  const float* Wv  = (const float*)d_in[8];  const float* bv  = (const float*)d_in[9];
  const float* Wv2 = (const float*)d_in[10]; const float* bv2 = (const float*)d_in[11];
  const float* Wz  = (const float*)d_in[12]; const float* bz  = (const float*)d_in[13];
  const float* Wm  = (const float*)d_in[14]; const float* bm  = (const float*)d_in[15];

  const size_t NPIX = (size_t)BB*NSEQ*DD;  // 1,179,648

  u16* ws = (u16*)d_ws;
  u16* WtQ  = ws + 0;            // all 7 packed weights contiguous: 663552 u16
  u16* WtK  = ws + 36864;
  u16* WtK2 = ws + 73728;
  u16* WtV  = ws + 110592;
  u16* WtV2 = ws + 147456;
  u16* WtZ  = ws + 184320;
  u16* WtM  = ws + 331776;
  u16* slotA = ws + 663552;      // q;   later Z low half
  u16* slotB = slotA + NPIX;     // k_h; later Z high half
  u16* slotC = slotB + NPIX;     // v_h^T [b][d][seq]
  u16* slotD = slotC + NPIX;     // k_m
  u16* slotE = slotD + NPIX;     // v_m^T [b][d][seq]
  u16* pox   = slotE + NPIX;     // partial regions 4..5 (2 NPIX)
  float2* ml = (float2*)(pox + 2*NPIX);   // 6*BB*NSEQ float2; total ws 18.7 MB
  u16* Zb    = slotA;            // 2*NPIX spanning A+B

  float* outh = (float*)d_out;   // final new_h (f32)
  float* outm = outh + NPIX;     // final new_m (f32)
  u16* po = (u16*)d_out;         // partial regions 0..3 (4 NPIX u16)
  u16* zh = po;                  // after combine: z_h
  u16* zm = po + NPIX;           // after combine: z_m

  WtSrcs wsrc;
  wsrc.src[0]=Wq; wsrc.src[1]=Wk; wsrc.src[2]=Wk2; wsrc.src[3]=Wv; wsrc.src[4]=Wv2;
  wsrc.src[5]=Wz; wsrc.src[6]=Wm;
  wtrans_all<<<dim3(2592), 256, 0, stream>>>(wsrc, ws);

  ConvPtrs ph;
  ph.W[0]=WtQ;  ph.W[1]=WtK;  ph.W[2]=WtV;
  ph.bias[0]=bq; ph.bias[1]=bk; ph.bias[2]=bv;
  ph.out[0]=slotA; ph.out[1]=slotB; ph.out[2]=slotC;
  ph.vt[0]=0; ph.vt[1]=0; ph.vt[2]=1;
  ph.nc = 3;

  ConvPtrs pm;
  pm.W[0]=WtK2; pm.W[1]=WtV2; pm.W[2]=WtV2;
  pm.bias[0]=bk2; pm.bias[1]=bv2; pm.bias[2]=bv2;
  pm.out[0]=slotD; pm.out[1]=slotE; pm.out[2]=slotE;
  pm.vt[0]=0; pm.vt[1]=1; pm.vt[2]=1;
  pm.nc = 2;

  // both conv64 streams, pixel-tiled: z = stream*3 + tile
  conv64_mfma<<<dim3(BB*HH, 1, 6), 256, 0, stream>>>(h, m, ph, pm);

  // stream-split + 3-way split-K attention -> partials (d_out + ws) + l in ws
  attn2_mfma<<<dim3(NSEQ/64, BB, 6), 256, 0, stream>>>(
      slotA, slotB, slotC, slotD, slotE, po, pox, ml);

  // combine chunk triples -> z_h, z_m (in d_out)
  attn_combine<<<dim3(2048), 256, 0, stream>>>(po, pox, ml);

  // Z = conv(concat(z_h, z_m)) -> bf16 into Zb; pixel-tiled + packed weights
  bigconv_mfma<128,128,64,false,false><<<dim3(BB*HH, 1, 3), 256, 0, stream>>>(
      zh, zm, (const float*)0, WtZ, bz, (void*)Zb, (void*)0, (const float*)0);

  // combined = conv(concat(Z, h)); fused gating -> f32 outputs; pixel-tiled
  bigconv_mfma<192,192,128,true,true><<<dim3(BB*HH, 1, 3), 256, 0, stream>>>(
      Zb, (const u16*)0, h, WtM, bm, (void*)outh, (void*)outm, m);
}

// Round 25
// 135.192 us; speedup vs baseline: 1.0930x; 1.0930x over previous
//
#include <hip/hip_runtime.h>

#define BB 8
#define HH 48
#define WW 48
#define DD 64
#define NSEQ (HH*WW)   // 2304

typedef unsigned short u16;
typedef unsigned long long u64;
typedef __attribute__((ext_vector_type(8))) short short8;
typedef __attribute__((ext_vector_type(4))) float f32x4;

__device__ __forceinline__ float bf2f(u16 u){ return __uint_as_float(((unsigned)u)<<16); }
__device__ __forceinline__ u16 f2bf(float f){
  unsigned u = __float_as_uint(f);
  return (u16)((u + 0x7fffu + ((u>>16)&1u)) >> 16);   // RNE
}
__device__ __forceinline__ f32x4 mfma16(short8 a, short8 b, f32x4 c){
  return __builtin_amdgcn_mfma_f32_16x16x32_bf16(a, b, c, 0, 0, 0);
}

// ------- fused weight transpose -> MFMA-FRAGMENT-PACKED bf16 --------------------------
// dst layout per tensor: [kpos][cot][ks][lane][8], elem = W[ci=ks*32+(lane>>4)*8+j][co=cot*16+(lane&15)]
struct WtSrcs { const float* src[7]; };
__global__ __launch_bounds__(256) void wtrans_all(WtSrcs s, u16* __restrict__ dst){
  int i = blockIdx.x*256 + threadIdx.x;       // total 663552
  if(i >= 663552) return;
  const float* sp; int local, CI, CO;
  if(i < 184320){ int seg = i/36864; local = i - seg*36864; sp = s.src[seg]; CI = 64; CO = 64; }
  else if(i < 331776){ local = i - 184320; sp = s.src[5]; CI = 128; CO = 128; }
  else { local = i - 331776; sp = s.src[6]; CI = 192; CO = 192; }
  int j    = local & 7;
  int lane = (local >> 3) & 63;
  int blk  = local >> 9;                      // (kpos*(CO/16)+cot)*(CI/32)+ks
  int nks  = CI/32;
  int ks   = blk % nks;
  int rem  = blk / nks;
  int cot  = rem % (CO/16);
  int kpos = rem / (CO/16);
  int ci = ks*32 + (lane>>4)*8 + j;
  int co = cot*16 + (lane&15);
  dst[i] = f2bf(sp[((size_t)kpos*CI + ci)*CO + co]);
}

// ----- merged multi-conv 64->64 (MFMA): blockIdx.z=0 -> h stream, =1 -> m stream ------
struct ConvPtrs {
  const u16*   W[3];     // packed bf16
  const float* bias[3];  // f32
  u16*         out[3];   // bf16
  int          vt[3];    // 1 -> write transposed [b][co][seq]
  int          nc;       // active weight sets
};

__global__ __launch_bounds__(256) void conv64_mfma(
    const float* __restrict__ in0, const float* __restrict__ in1,
    ConvPtrs p0, ConvPtrs p1){
  const int SP = 72;
  __shared__ u16 lds[3][WW+2][SP];
  const float* in = blockIdx.z ? in1 : in0;
  ConvPtrs p = blockIdx.z ? p1 : p0;
  const int b = blockIdx.x / HH, y = blockIdx.x % HH;
  const int tid  = threadIdx.x;
  const int wave = tid >> 6, lane = tid & 63, g = lane >> 4, col = lane & 15;
  const short8 Z8 = {0,0,0,0,0,0,0,0};

  for(int ky=0; ky<3; ky++){
    int ys = y + ky - 1;
    const int NCH = WW*64/8;
    if(ys < 0 || ys >= HH){
      for(int c8 = tid; c8 < NCH; c8 += 256){
        int px = c8 >> 3, cb = (c8 & 7)*8;
        *(short8*)&lds[ky][px+1][cb] = Z8;
      }
    } else {
      const float* rowp = in + (size_t)(b*HH + ys)*WW*64;
      for(int c8 = tid; c8 < NCH; c8 += 256){
        int px = c8 >> 3, cb = (c8 & 7)*8;
        short8 v;
        #pragma unroll
        for(int j=0;j<8;j++) v[j] = (short)f2bf(rowp[px*64 + cb + j]);
        *(short8*)&lds[ky][px+1][cb] = v;
      }
    }
    for(int c8 = tid; c8 < 16; c8 += 256){
      int which = c8 >> 3; int cb = (c8 & 7)*8;
      *(short8*)&lds[ky][which ? (WW+1) : 0][cb] = Z8;
    }
  }
  __syncthreads();

  const f32x4 zf = {0.f,0.f,0.f,0.f};
  f32x4 acc[3][3];
  #pragma unroll
  for(int mt=0; mt<3; mt++)
    #pragma unroll
    for(int c=0; c<3; c++) acc[mt][c] = zf;

  const int nc = p.nc;
  #pragma unroll
  for(int ky=0; ky<3; ky++)
  #pragma unroll
  for(int kx=0; kx<3; kx++)
  #pragma unroll
  for(int ks=0; ks<2; ks++){
    short8 a[3];
    #pragma unroll
    for(int mt=0; mt<3; mt++)
      a[mt] = *(const short8*)&lds[ky][mt*16 + col + kx][ks*32 + g*8];
    #pragma unroll
    for(int c=0; c<3; c++){
      if(c < nc){
        const u16* wp = p.W[c] + ((((ky*3+kx)*4 + wave)*2 + ks)<<9) + lane*8;
        short8 bfr = *(const short8*)wp;
        #pragma unroll
        for(int mt=0; mt<3; mt++)
          acc[mt][c] = mfma16(a[mt], bfr, acc[mt][c]);
      }
    }
  }

  #pragma unroll
  for(int c=0; c<3; c++){
    if(c >= nc) continue;
    int co = wave*16 + col;
    float bs = p.bias[c][co];
    if(p.vt[c]){
      u16* op = p.out[c] + ((size_t)(b*64 + co))*NSEQ + (size_t)y*WW;
      #pragma unroll
      for(int mt=0; mt<3; mt++){
        int px = mt*16 + g*4;
        u64 pk =  (u64)f2bf(acc[mt][c][0] + bs)
               | ((u64)f2bf(acc[mt][c][1] + bs) << 16)
               | ((u64)f2bf(acc[mt][c][2] + bs) << 32)
               | ((u64)f2bf(acc[mt][c][3] + bs) << 48);
        *(u64*)&op[px] = pk;
      }
    } else {
      u16* op = p.out[c] + ((size_t)(b*HH + y)*WW)*64 + co;
      #pragma unroll
      for(int mt=0; mt<3; mt++)
        #pragma unroll
        for(int r=0; r<4; r++){
          int px = mt*16 + g*4 + r;
          op[(size_t)px*64] = f2bf(acc[mt][c][r] + bs);
        }
    }
  }
}

// ------- split-K single-stream flash attention: QBLK=64, 4 strip-waves ---------------
// FIXED-MAX softmax (m == 0): P = exp(S). Row-sums l via MFMA against a ones-tile.
__global__ __launch_bounds__(256) void attn2_mfma(
    const u16* __restrict__ q,
    const u16* __restrict__ kh, const u16* __restrict__ vhT,
    const u16* __restrict__ km2, const u16* __restrict__ vmT,
    u16* __restrict__ po, u16* __restrict__ pox, float2* __restrict__ ml){
  __shared__ u16 Ks [64*64];    // [key][d] swizzled
  __shared__ u16 Vts[80*64];    // [d][key] swizzled; rows 64..79 = ones
  __shared__ u16 Ps [64*64];    // [qrow][key] swizzled (wave-private strips)
  const int qt = blockIdx.x, b = blockIdx.y;
  const int s = blockIdx.z / 3, ch = blockIdx.z % 3;
  const int tid = threadIdx.x, wave = tid>>6, lane = tid&63;
  const int g = lane>>4, col = lane&15;
  const int strip = wave;
  const size_t NP = (size_t)BB*NSEQ*DD;

  const u16* kk = s ? km2 : kh;
  const u16* vT = s ? vmT : vhT;

  const u16* qp = q + ((size_t)(b*NSEQ + qt*64 + strip*16 + col))*DD;
  short8 aq0 = *(const short8*)&qp[g*8];
  short8 aq1 = *(const short8*)&qp[32 + g*8];

  const int r0a = tid>>3, gr = tid&7, cb0 = gr*8;
  const int r0b = r0a + 32;
  const int stA = r0a*64 + ((gr ^ (r0a&7))<<3);
  const int stB = stA + 32*64;
  const size_t tb  = (size_t)(b*NSEQ)*DD;
  const size_t tbT = (size_t)(b*64)*NSEQ;

  const int cg0 = ((g     ^ (col&7))<<3);
  const int cg1 = (((4+g) ^ (col&7))<<3);

  for(int idx = tid; idx < 16*64; idx += 256) Vts[64*64 + idx] = 0x3F80;  // bf16 1.0

  short8 paK0,paK1,paV0,paV1;
  short8 pbK0,pbK1,pbV0,pbV1;

  const f32x4 zf = {0.f,0.f,0.f,0.f};
  f32x4 o[4];
  #pragma unroll
  for(int nt=0; nt<4; nt++) o[nt] = zf;
  f32x4 ol = zf;                               // l accumulator

#define BAR() { __builtin_amdgcn_s_barrier(); __builtin_amdgcn_sched_barrier(0); }
#define LWAIT() { asm volatile("s_waitcnt lgkmcnt(0)" ::: "memory"); __builtin_amdgcn_sched_barrier(0); }

#define LOADSET(K0,K1,V0,V1, kt_) {                                        \
    size_t offK0 = tb + (size_t)(kt_)*64*DD + (size_t)r0a*DD + cb0;        \
    size_t offK1 = tb + (size_t)(kt_)*64*DD + (size_t)r0b*DD + cb0;        \
    size_t offV0 = tbT + (size_t)r0a*NSEQ + (size_t)(kt_)*64 + cb0;        \
    size_t offV1 = tbT + (size_t)r0b*NSEQ + (size_t)(kt_)*64 + cb0;        \
    K0 = *(const short8*)&kk[offK0];  K1 = *(const short8*)&kk[offK1];     \
    V0 = *(const short8*)&vT[offV0];  V1 = *(const short8*)&vT[offV1];     \
  }
#define STORESET(K0,K1,V0,V1) {                                            \
    *(short8*)&Ks [stA] = K0;   *(short8*)&Ks [stB] = K1;                  \
    *(short8*)&Vts[stA] = V0;   *(short8*)&Vts[stB] = V1;                  \
  }
#define COMPUTE() {                                                 \
    __builtin_amdgcn_s_setprio(1);                                  \
    f32x4 sv[4];                                                    \
    _Pragma("unroll")                                               \
    for(int nt=0; nt<4; nt++){                                      \
      sv[nt] = zf;                                                  \
      int rowb = (nt*16 + col)*64;                                  \
      short8 bk0 = *(const short8*)&Ks[rowb + cg0];                 \
      sv[nt] = mfma16(aq0, bk0, sv[nt]);                            \
      short8 bk1 = *(const short8*)&Ks[rowb + cg1];                 \
      sv[nt] = mfma16(aq1, bk1, sv[nt]);                            \
    }                                                               \
    _Pragma("unroll")                                               \
    for(int r=0; r<4; r++){                                         \
      int prow = strip*16 + g*4 + r;                                \
      int pbase = prow*64;                                          \
      _Pragma("unroll")                                             \
      for(int nt=0; nt<4; nt++)                                     \
        Ps[pbase + (((nt*2 + (col>>3)) ^ (prow&7))<<3) + (col&7)] = f2bf(__expf(sv[nt][r])); \
    }                                                               \
    int prowr = strip*16 + col;                                     \
    _Pragma("unroll")                                               \
    for(int ks=0; ks<2; ks++){                                      \
      short8 ap = *(const short8*)&Ps[prowr*64 + (ks ? cg1 : cg0)]; \
      _Pragma("unroll")                                             \
      for(int nt=0; nt<4; nt++){                                    \
        short8 bv = *(const short8*)&Vts[(nt*16 + col)*64 + (ks ? cg1 : cg0)]; \
        o[nt] = mfma16(ap, bv, o[nt]);                              \
      }                                                             \
      short8 b1 = *(const short8*)&Vts[(64 + col)*64 + (ks ? cg1 : cg0)]; \
      ol = mfma16(ap, b1, ol);                                      \
    }                                                               \
    __builtin_amdgcn_s_setprio(0);                                  \
  }

  const int kt0 = ch*12;                     // 12 tiles of 64 keys per chunk
  LOADSET(paK0,paK1,paV0,paV1, kt0);
  for(int kt = kt0; kt < kt0+12; kt += 2){
    LOADSET(pbK0,pbK1,pbV0,pbV1, kt+1);
    BAR();
    STORESET(paK0,paK1,paV0,paV1);
    LWAIT();
    BAR();
    COMPUTE();
    if(kt+2 < kt0+12) LOADSET(paK0,paK1,paV0,paV1, kt+2);
    BAR();
    STORESET(pbK0,pbK1,pbV0,pbV1);
    LWAIT();
    BAR();
    COMPUTE();
  }

  const int ridx = s*3 + ch;
  u16* rbase = (ridx < 4) ? (po + (size_t)ridx*NP) : (pox + (size_t)(ridx-4)*NP);
  u16* pb = rbase + ((size_t)(b*NSEQ + qt*64 + strip*16))*DD;
  #pragma unroll
  for(int nt=0; nt<4; nt++)
    #pragma unroll
    for(int r=0; r<4; r++)
      pb[(g*4 + r)*DD + nt*16 + col] = f2bf(o[nt][r]);
  if(col == 0){
    #pragma unroll
    for(int r=0; r<4; r++){
      int qrow = qt*64 + strip*16 + g*4 + r;
      float2 v; v.x = 0.f; v.y = ol[r];
      ml[(size_t)ridx*BB*NSEQ + (size_t)b*NSEQ + qrow] = v;
    }
  }
#undef LOADSET
#undef STORESET
#undef COMPUTE
#undef BAR
#undef LWAIT
}

// ------- combine 3 KV-chunks per stream (all m=0): z_h -> po 0, z_m -> po 1 -----------
__global__ __launch_bounds__(256) void attn_combine(u16* po, const u16* __restrict__ pox,
                                                    const float2* __restrict__ ml){
  const size_t NP = (size_t)BB*NSEQ*DD;
  const size_t RORD = (size_t)BB*NSEQ;
  for(size_t e = (size_t)blockIdx.x*256 + threadIdx.x; e < NP; e += (size_t)gridDim.x*256){
    size_t row = e / DD;
    float lh = ml[row].y + ml[RORD + row].y + ml[2*RORD + row].y;
    float lm = ml[3*RORD + row].y + ml[4*RORD + row].y + ml[5*RORD + row].y;
    float oh = bf2f(po[e]) + bf2f(po[NP + e]) + bf2f(po[2*NP + e]);
    float om = bf2f(po[3*NP + e]) + bf2f(pox[e]) + bf2f(pox[NP + e]);
    po[e]      = f2bf(oh/lh);   // z_h
    po[NP + e] = f2bf(om/lm);   // z_m (overwrites h-c1; this thread read it already)
  }
}

// -------- big conv (MFMA), PIXEL-TILED + packed weights: blockIdx.z = 16-px tile ------
// LDS = [3][18][CIN+8] (16 px + 2 halo). Each wave: 1 pixel tile x NTW co-tiles.
template<int CIN, int COUT, int SPLIT, bool GATE, bool IN1F>
__global__ __launch_bounds__(256) void bigconv_mfma(
    const u16* __restrict__ in0, const u16* __restrict__ in1b, const float* __restrict__ in1f,
    const u16* __restrict__ Wt, const float* __restrict__ bias,
    void* __restrict__ out0v, void* __restrict__ out1v, const float* __restrict__ mem){
  constexpr int SP  = CIN + 8;
  constexpr int NTW = COUT/64;
  __shared__ u16 lds[3][18][SP];
  const int b = blockIdx.x / HH, y = blockIdx.x % HH;
  const int pt = blockIdx.z;                 // pixel tile: global px0 = pt*16
  const int tid  = threadIdx.x;
  const int wave = tid >> 6, lane = tid & 63, g = lane >> 4, col = lane & 15;
  const short8 Z8 = {0,0,0,0,0,0,0,0};

  for(int ky=0; ky<3; ky++){
    int ys = y + ky - 1;
    const int NCH = 18*CIN/8;
    if(ys < 0 || ys >= HH){
      for(int c8 = tid; c8 < NCH; c8 += 256){
        int px = c8 / (CIN/8), cb = (c8 % (CIN/8))*8;
        *(short8*)&lds[ky][px][cb] = Z8;
      }
    } else {
      size_t base0 = (size_t)(b*HH + ys)*WW*SPLIT;
      size_t base1 = (size_t)(b*HH + ys)*WW*(CIN-SPLIT);
      for(int c8 = tid; c8 < NCH; c8 += 256){
        int px = c8 / (CIN/8), cb = (c8 % (CIN/8))*8;
        int x = pt*16 + px - 1;
        short8 val;
        if(x < 0 || x >= WW){
          val = Z8;
        } else if(cb < SPLIT){
          val = *(const short8*)&in0[base0 + (size_t)x*SPLIT + cb];
        } else if constexpr (IN1F){
          const float* sp = &in1f[base1 + (size_t)x*(CIN-SPLIT) + cb - SPLIT];
          #pragma unroll
          for(int j=0;j<8;j++) val[j] = (short)f2bf(sp[j]);
        } else {
          val = *(const short8*)&in1b[base1 + (size_t)x*(CIN-SPLIT) + cb - SPLIT];
        }
        *(short8*)&lds[ky][px][cb] = val;
      }
    }
  }
  __syncthreads();

  const f32x4 zf = {0.f,0.f,0.f,0.f};
  f32x4 acc[NTW];
  #pragma unroll
  for(int i=0; i<NTW; i++) acc[i] = zf;

  #pragma unroll
  for(int ky=0; ky<3; ky++)
  #pragma unroll
  for(int kx=0; kx<3; kx++)
  #pragma unroll
  for(int ks=0; ks<CIN/32; ks++){
    short8 a = *(const short8*)&lds[ky][col + kx][ks*32 + g*8];
    #pragma unroll
    for(int i=0; i<NTW; i++){
      // packed: (((kpos*(COUT/16) + cot)*(CIN/32) + ks)<<9) + lane*8, cot = wave + 4*i
      const u16* wp = Wt + (((((ky*3+kx)*(COUT/16)) + (wave + 4*i))*(CIN/32) + ks)<<9) + lane*8;
      short8 bfr = *(const short8*)wp;
      acc[i] = mfma16(a, bfr, acc[i]);
    }
  }

  if constexpr (!GATE){
    u16* out0 = (u16*)out0v;
    #pragma unroll
    for(int i=0; i<NTW; i++){
      int co = (wave + 4*i)*16 + col;
      float bs = bias[co];
      u16* op = out0 + (size_t)(b*HH + y)*WW*COUT + co;
      #pragma unroll
      for(int r=0; r<4; r++){
        int px = pt*16 + g*4 + r;
        op[(size_t)px*COUT] = f2bf(acc[i][r] + bs);
      }
    }
  } else {
    float* oh = (float*)out0v;
    float* om = (float*)out1v;
    int c = wave*16 + col;
    float bo = bias[c], bg = bias[64+c], bgi = bias[128+c];
    #pragma unroll
    for(int r=0; r<4; r++){
      int px = pt*16 + g*4 + r;
      size_t idx = ((size_t)(b*HH + y)*WW + px)*64 + c;
      float mo = acc[0][r] + bo;
      float mg = acc[1][r] + bg;
      float gi = acc[2][r] + bgi;
      float mval = mem[idx];
      float si = 1.f/(1.f + __expf(-gi));
      float nm = (1.f - si)*mval + si*tanhf(mg);
      float nh = (1.f/(1.f + __expf(-mo)))*nm;
      oh[idx] = nh;
      om[idx] = nm;
    }
  }
}

// ---------------- launcher ----------------
extern "C" void kernel_launch(void* const* d_in, const int* in_sizes, int n_in,
                              void* d_out, int out_size, void* d_ws, size_t ws_size,
                              hipStream_t stream){
  (void)in_sizes; (void)n_in; (void)out_size; (void)ws_size;
  const float* h   = (const float*)d_in[0];
  const float* m   = (const float*)d_in[1];
  const float* Wq  = (const float*)d_in[2];  const float* bq  = (const float*)d_in[3];
  const float* Wk  = (const float*)d_in[4];  const float* bk  = (const float*)d_in[5];
  const float* Wk2 = (const float*)d_in[6];  const float* bk2 = (const float*)d_in[7];
  const float* Wv  = (const float*)d_in[8];  const float* bv  = (const float*)d_in[9];
  const float* Wv2 = (const float*)d_in[10]; const float* bv2 = (const float*)d_in[11];
  const float* Wz  = (const float*)d_in[12]; const float* bz  = (const float*)d_in[13];
  const float* Wm  = (const float*)d_in[14]; const float* bm  = (const float*)d_in[15];

  const size_t NPIX = (size_t)BB*NSEQ*DD;  // 1,179,648

  u16* ws = (u16*)d_ws;
  u16* WtQ  = ws + 0;            // all 7 packed weights contiguous: 663552 u16
  u16* WtK  = ws + 36864;
  u16* WtK2 = ws + 73728;
  u16* WtV  = ws + 110592;
  u16* WtV2 = ws + 147456;
  u16* WtZ  = ws + 184320;
  u16* WtM  = ws + 331776;
  u16* slotA = ws + 663552;      // q;   later Z low half
  u16* slotB = slotA + NPIX;     // k_h; later Z high half
  u16* slotC = slotB + NPIX;     // v_h^T [b][d][seq]
  u16* slotD = slotC + NPIX;     // k_m
  u16* slotE = slotD + NPIX;     // v_m^T [b][d][seq]
  u16* pox   = slotE + NPIX;     // partial regions 4..5 (2 NPIX)
  float2* ml = (float2*)(pox + 2*NPIX);   // 6*BB*NSEQ float2; total ws 18.7 MB
  u16* Zb    = slotA;            // 2*NPIX spanning A+B

  float* outh = (float*)d_out;   // final new_h (f32)
  float* outm = outh + NPIX;     // final new_m (f32)
  u16* po = (u16*)d_out;         // partial regions 0..3 (4 NPIX u16)
  u16* zh = po;                  // after combine: z_h
  u16* zm = po + NPIX;           // after combine: z_m

  WtSrcs wsrc;
  wsrc.src[0]=Wq; wsrc.src[1]=Wk; wsrc.src[2]=Wk2; wsrc.src[3]=Wv; wsrc.src[4]=Wv2;
  wsrc.src[5]=Wz; wsrc.src[6]=Wm;
  wtrans_all<<<dim3(2592), 256, 0, stream>>>(wsrc, ws);

  ConvPtrs ph;
  ph.W[0]=WtQ;  ph.W[1]=WtK;  ph.W[2]=WtV;
  ph.bias[0]=bq; ph.bias[1]=bk; ph.bias[2]=bv;
  ph.out[0]=slotA; ph.out[1]=slotB; ph.out[2]=slotC;
  ph.vt[0]=0; ph.vt[1]=0; ph.vt[2]=1;
  ph.nc = 3;

  ConvPtrs pm;
  pm.W[0]=WtK2; pm.W[1]=WtV2; pm.W[2]=WtV2;
  pm.bias[0]=bk2; pm.bias[1]=bv2; pm.bias[2]=bv2;
  pm.out[0]=slotD; pm.out[1]=slotE; pm.out[2]=slotE;
  pm.vt[0]=0; pm.vt[1]=1; pm.vt[2]=1;
  pm.nc = 2;

  // both conv64 streams in one dispatch (z: 0=h, 1=m)
  conv64_mfma<<<dim3(BB*HH, 1, 2), 256, 0, stream>>>(h, m, ph, pm);

  // stream-split + 3-way split-K attention -> partials (d_out + ws) + l in ws
  attn2_mfma<<<dim3(NSEQ/64, BB, 6), 256, 0, stream>>>(
      slotA, slotB, slotC, slotD, slotE, po, pox, ml);

  // combine chunk triples -> z_h, z_m (in d_out)
  attn_combine<<<dim3(2048), 256, 0, stream>>>(po, pox, ml);

  // Z = conv(concat(z_h, z_m)) -> bf16 into Zb; pixel-tiled + packed weights
  bigconv_mfma<128,128,64,false,false><<<dim3(BB*HH, 1, 3), 256, 0, stream>>>(
      zh, zm, (const float*)0, WtZ, bz, (void*)Zb, (void*)0, (const float*)0);

  // combined = conv(concat(Z, h)); fused gating -> f32 outputs; pixel-tiled
  bigconv_mfma<192,192,128,true,true><<<dim3(BB*HH, 1, 3), 256, 0, stream>>>(
      Zb, (const u16*)0, h, WtM, bm, (void*)outh, (void*)outm, m);
}

// Round 26
// 133.248 us; speedup vs baseline: 1.1090x; 1.0146x over previous
//
#include <hip/hip_runtime.h>

#define BB 8
#define HH 48
#define WW 48
#define DD 64
#define NSEQ (HH*WW)   // 2304

typedef unsigned short u16;
typedef unsigned long long u64;
typedef __attribute__((ext_vector_type(8))) short short8;
typedef __attribute__((ext_vector_type(4))) float f32x4;

__device__ __forceinline__ float bf2f(u16 u){ return __uint_as_float(((unsigned)u)<<16); }
__device__ __forceinline__ u16 f2bf(float f){
  unsigned u = __float_as_uint(f);
  return (u16)((u + 0x7fffu + ((u>>16)&1u)) >> 16);   // RNE
}
__device__ __forceinline__ f32x4 mfma16(short8 a, short8 b, f32x4 c){
  return __builtin_amdgcn_mfma_f32_16x16x32_bf16(a, b, c, 0, 0, 0);
}

// ------- fused weight transpose -> MFMA-FRAGMENT-PACKED bf16 --------------------------
// dst layout per tensor: [kpos][cot][ks][lane][8], elem = W[ci=ks*32+(lane>>4)*8+j][co=cot*16+(lane&15)]
struct WtSrcs { const float* src[7]; };
__global__ __launch_bounds__(256) void wtrans_all(WtSrcs s, u16* __restrict__ dst){
  int i = blockIdx.x*256 + threadIdx.x;       // total 663552
  if(i >= 663552) return;
  const float* sp; int local, CI, CO;
  if(i < 184320){ int seg = i/36864; local = i - seg*36864; sp = s.src[seg]; CI = 64; CO = 64; }
  else if(i < 331776){ local = i - 184320; sp = s.src[5]; CI = 128; CO = 128; }
  else { local = i - 331776; sp = s.src[6]; CI = 192; CO = 192; }
  int j    = local & 7;
  int lane = (local >> 3) & 63;
  int blk  = local >> 9;                      // (kpos*(CO/16)+cot)*(CI/32)+ks
  int nks  = CI/32;
  int ks   = blk % nks;
  int rem  = blk / nks;
  int cot  = rem % (CO/16);
  int kpos = rem / (CO/16);
  int ci = ks*32 + (lane>>4)*8 + j;
  int co = cot*16 + (lane&15);
  dst[i] = f2bf(sp[((size_t)kpos*CI + ci)*CO + co]);
}

// ----- merged multi-conv 64->64 (MFMA): blockIdx.z=0 -> h stream, =1 -> m stream ------
struct ConvPtrs {
  const u16*   W[3];     // packed bf16
  const float* bias[3];  // f32
  u16*         out[3];   // bf16
  int          vt[3];    // 1 -> write transposed [b][co][seq]
  int          nc;       // active weight sets
};

__global__ __launch_bounds__(256) void conv64_mfma(
    const float* __restrict__ in0, const float* __restrict__ in1,
    ConvPtrs p0, ConvPtrs p1){
  const int SP = 72;
  __shared__ u16 lds[3][WW+2][SP];
  const float* in = blockIdx.z ? in1 : in0;
  ConvPtrs p = blockIdx.z ? p1 : p0;
  const int b = blockIdx.x / HH, y = blockIdx.x % HH;
  const int tid  = threadIdx.x;
  const int wave = tid >> 6, lane = tid & 63, g = lane >> 4, col = lane & 15;
  const short8 Z8 = {0,0,0,0,0,0,0,0};

  for(int ky=0; ky<3; ky++){
    int ys = y + ky - 1;
    const int NCH = WW*64/8;
    if(ys < 0 || ys >= HH){
      for(int c8 = tid; c8 < NCH; c8 += 256){
        int px = c8 >> 3, cb = (c8 & 7)*8;
        *(short8*)&lds[ky][px+1][cb] = Z8;
      }
    } else {
      const float* rowp = in + (size_t)(b*HH + ys)*WW*64;
      for(int c8 = tid; c8 < NCH; c8 += 256){
        int px = c8 >> 3, cb = (c8 & 7)*8;
        short8 v;
        #pragma unroll
        for(int j=0;j<8;j++) v[j] = (short)f2bf(rowp[px*64 + cb + j]);
        *(short8*)&lds[ky][px+1][cb] = v;
      }
    }
    for(int c8 = tid; c8 < 16; c8 += 256){
      int which = c8 >> 3; int cb = (c8 & 7)*8;
      *(short8*)&lds[ky][which ? (WW+1) : 0][cb] = Z8;
    }
  }
  __syncthreads();

  const f32x4 zf = {0.f,0.f,0.f,0.f};
  f32x4 acc[3][3];
  #pragma unroll
  for(int mt=0; mt<3; mt++)
    #pragma unroll
    for(int c=0; c<3; c++) acc[mt][c] = zf;

  const int nc = p.nc;
  #pragma unroll
  for(int ky=0; ky<3; ky++)
  #pragma unroll
  for(int kx=0; kx<3; kx++)
  #pragma unroll
  for(int ks=0; ks<2; ks++){
    short8 a[3];
    #pragma unroll
    for(int mt=0; mt<3; mt++)
      a[mt] = *(const short8*)&lds[ky][mt*16 + col + kx][ks*32 + g*8];
    #pragma unroll
    for(int c=0; c<3; c++){
      if(c < nc){
        const u16* wp = p.W[c] + ((((ky*3+kx)*4 + wave)*2 + ks)<<9) + lane*8;
        short8 bfr = *(const short8*)wp;
        #pragma unroll
        for(int mt=0; mt<3; mt++)
          acc[mt][c] = mfma16(a[mt], bfr, acc[mt][c]);
      }
    }
  }

  #pragma unroll
  for(int c=0; c<3; c++){
    if(c >= nc) continue;
    int co = wave*16 + col;
    float bs = p.bias[c][co];
    if(p.vt[c]){
      u16* op = p.out[c] + ((size_t)(b*64 + co))*NSEQ + (size_t)y*WW;
      #pragma unroll
      for(int mt=0; mt<3; mt++){
        int px = mt*16 + g*4;
        u64 pk =  (u64)f2bf(acc[mt][c][0] + bs)
               | ((u64)f2bf(acc[mt][c][1] + bs) << 16)
               | ((u64)f2bf(acc[mt][c][2] + bs) << 32)
               | ((u64)f2bf(acc[mt][c][3] + bs) << 48);
        *(u64*)&op[px] = pk;
      }
    } else {
      u16* op = p.out[c] + ((size_t)(b*HH + y)*WW)*64 + co;
      #pragma unroll
      for(int mt=0; mt<3; mt++)
        #pragma unroll
        for(int r=0; r<4; r++){
          int px = mt*16 + g*4 + r;
          op[(size_t)px*64] = f2bf(acc[mt][c][r] + bs);
        }
    }
  }
}

// ------- split-K single-stream flash attention: QBLK=64, 4 strip-waves ---------------
// FIXED-MAX softmax (m == 0): P = exp(S). Row-sums l via MFMA against a CONSTANT
// ones B-fragment in registers (no LDS ones-tile needed).
__global__ __launch_bounds__(256) void attn2_mfma(
    const u16* __restrict__ q,
    const u16* __restrict__ kh, const u16* __restrict__ vhT,
    const u16* __restrict__ km2, const u16* __restrict__ vmT,
    u16* __restrict__ po, u16* __restrict__ pox, float2* __restrict__ ml){
  __shared__ u16 Ks [64*64];    // [key][d] swizzled
  __shared__ u16 Vts[64*64];    // [d][key] swizzled
  __shared__ u16 Ps [64*64];    // [qrow][key] swizzled (wave-private strips)
  const int qt = blockIdx.x, b = blockIdx.y;
  const int s = blockIdx.z / 3, ch = blockIdx.z % 3;
  const int tid = threadIdx.x, wave = tid>>6, lane = tid&63;
  const int g = lane>>4, col = lane&15;
  const int strip = wave;
  const size_t NP = (size_t)BB*NSEQ*DD;

  const u16* kk = s ? km2 : kh;
  const u16* vT = s ? vmT : vhT;

  const u16* qp = q + ((size_t)(b*NSEQ + qt*64 + strip*16 + col))*DD;
  short8 aq0 = *(const short8*)&qp[g*8];
  short8 aq1 = *(const short8*)&qp[32 + g*8];

  const int r0a = tid>>3, gr = tid&7, cb0 = gr*8;
  const int r0b = r0a + 32;
  const int stA = r0a*64 + ((gr ^ (r0a&7))<<3);
  const int stB = stA + 32*64;
  const size_t tb  = (size_t)(b*NSEQ)*DD;
  const size_t tbT = (size_t)(b*64)*NSEQ;

  const int cg0 = ((g     ^ (col&7))<<3);
  const int cg1 = (((4+g) ^ (col&7))<<3);

  const short ONE = (short)0x3F80;             // bf16 1.0
  const short8 B1 = {ONE,ONE,ONE,ONE,ONE,ONE,ONE,ONE};

  short8 paK0,paK1,paV0,paV1;
  short8 pbK0,pbK1,pbV0,pbV1;

  const f32x4 zf = {0.f,0.f,0.f,0.f};
  f32x4 o[4];
  #pragma unroll
  for(int nt=0; nt<4; nt++) o[nt] = zf;
  f32x4 ol = zf;                               // l accumulator

#define BAR() { __builtin_amdgcn_s_barrier(); __builtin_amdgcn_sched_barrier(0); }
#define LWAIT() { asm volatile("s_waitcnt lgkmcnt(0)" ::: "memory"); __builtin_amdgcn_sched_barrier(0); }

#define LOADSET(K0,K1,V0,V1, kt_) {                                        \
    size_t offK0 = tb + (size_t)(kt_)*64*DD + (size_t)r0a*DD + cb0;        \
    size_t offK1 = tb + (size_t)(kt_)*64*DD + (size_t)r0b*DD + cb0;        \
    size_t offV0 = tbT + (size_t)r0a*NSEQ + (size_t)(kt_)*64 + cb0;        \
    size_t offV1 = tbT + (size_t)r0b*NSEQ + (size_t)(kt_)*64 + cb0;        \
    K0 = *(const short8*)&kk[offK0];  K1 = *(const short8*)&kk[offK1];     \
    V0 = *(const short8*)&vT[offV0];  V1 = *(const short8*)&vT[offV1];     \
  }
#define STORESET(K0,K1,V0,V1) {                                            \
    *(short8*)&Ks [stA] = K0;   *(short8*)&Ks [stB] = K1;                  \
    *(short8*)&Vts[stA] = V0;   *(short8*)&Vts[stB] = V1;                  \
  }
#define COMPUTE() {                                                 \
    __builtin_amdgcn_s_setprio(1);                                  \
    f32x4 sv[4];                                                    \
    _Pragma("unroll")                                               \
    for(int nt=0; nt<4; nt++){                                      \
      sv[nt] = zf;                                                  \
      int rowb = (nt*16 + col)*64;                                  \
      short8 bk0 = *(const short8*)&Ks[rowb + cg0];                 \
      sv[nt] = mfma16(aq0, bk0, sv[nt]);                            \
      short8 bk1 = *(const short8*)&Ks[rowb + cg1];                 \
      sv[nt] = mfma16(aq1, bk1, sv[nt]);                            \
    }                                                               \
    _Pragma("unroll")                                               \
    for(int r=0; r<4; r++){                                         \
      int prow = strip*16 + g*4 + r;                                \
      int pbase = prow*64;                                          \
      _Pragma("unroll")                                             \
      for(int nt=0; nt<4; nt++)                                     \
        Ps[pbase + (((nt*2 + (col>>3)) ^ (prow&7))<<3) + (col&7)] = f2bf(__expf(sv[nt][r])); \
    }                                                               \
    int prowr = strip*16 + col;                                     \
    _Pragma("unroll")                                               \
    for(int ks=0; ks<2; ks++){                                      \
      short8 ap = *(const short8*)&Ps[prowr*64 + (ks ? cg1 : cg0)]; \
      _Pragma("unroll")                                             \
      for(int nt=0; nt<4; nt++){                                    \
        short8 bv = *(const short8*)&Vts[(nt*16 + col)*64 + (ks ? cg1 : cg0)]; \
        o[nt] = mfma16(ap, bv, o[nt]);                              \
      }                                                             \
      ol = mfma16(ap, B1, ol);                                      \
    }                                                               \
    __builtin_amdgcn_s_setprio(0);                                  \
  }

  const int kt0 = ch*12;                     // 12 tiles of 64 keys per chunk
  LOADSET(paK0,paK1,paV0,paV1, kt0);
  for(int kt = kt0; kt < kt0+12; kt += 2){
    LOADSET(pbK0,pbK1,pbV0,pbV1, kt+1);
    BAR();
    STORESET(paK0,paK1,paV0,paV1);
    LWAIT();
    BAR();
    COMPUTE();
    if(kt+2 < kt0+12) LOADSET(paK0,paK1,paV0,paV1, kt+2);
    BAR();
    STORESET(pbK0,pbK1,pbV0,pbV1);
    LWAIT();
    BAR();
    COMPUTE();
  }

  const int ridx = s*3 + ch;
  u16* rbase = (ridx < 4) ? (po + (size_t)ridx*NP) : (pox + (size_t)(ridx-4)*NP);
  u16* pb = rbase + ((size_t)(b*NSEQ + qt*64 + strip*16))*DD;
  #pragma unroll
  for(int nt=0; nt<4; nt++)
    #pragma unroll
    for(int r=0; r<4; r++)
      pb[(g*4 + r)*DD + nt*16 + col] = f2bf(o[nt][r]);
  if(col == 0){
    #pragma unroll
    for(int r=0; r<4; r++){
      int qrow = qt*64 + strip*16 + g*4 + r;
      float2 v; v.x = 0.f; v.y = ol[r];
      ml[(size_t)ridx*BB*NSEQ + (size_t)b*NSEQ + qrow] = v;
    }
  }
#undef LOADSET
#undef STORESET
#undef COMPUTE
#undef BAR
#undef LWAIT
}

// ------- combine 3 KV-chunks per stream (all m=0): z_h -> po 0, z_m -> po 1 -----------
__global__ __launch_bounds__(256) void attn_combine(u16* po, const u16* __restrict__ pox,
                                                    const float2* __restrict__ ml){
  const size_t NP = (size_t)BB*NSEQ*DD;
  const size_t RORD = (size_t)BB*NSEQ;
  for(size_t e = (size_t)blockIdx.x*256 + threadIdx.x; e < NP; e += (size_t)gridDim.x*256){
    size_t row = e / DD;
    float lh = ml[row].y + ml[RORD + row].y + ml[2*RORD + row].y;
    float lm = ml[3*RORD + row].y + ml[4*RORD + row].y + ml[5*RORD + row].y;
    float oh = bf2f(po[e]) + bf2f(po[NP + e]) + bf2f(po[2*NP + e]);
    float om = bf2f(po[3*NP + e]) + bf2f(pox[e]) + bf2f(pox[NP + e]);
    po[e]      = f2bf(oh/lh);   // z_h
    po[NP + e] = f2bf(om/lm);   // z_m (overwrites h-c1; this thread read it already)
  }
}

// -------- big conv (MFMA), PIXEL-TILED + packed weights: blockIdx.z = 16-px tile ------
template<int CIN, int COUT, int SPLIT, bool GATE, bool IN1F>
__global__ __launch_bounds__(256) void bigconv_mfma(
    const u16* __restrict__ in0, const u16* __restrict__ in1b, const float* __restrict__ in1f,
    const u16* __restrict__ Wt, const float* __restrict__ bias,
    void* __restrict__ out0v, void* __restrict__ out1v, const float* __restrict__ mem){
  constexpr int SP  = CIN + 8;
  constexpr int NTW = COUT/64;
  __shared__ u16 lds[3][18][SP];
  const int b = blockIdx.x / HH, y = blockIdx.x % HH;
  const int pt = blockIdx.z;                 // pixel tile: global px0 = pt*16
  const int tid  = threadIdx.x;
  const int wave = tid >> 6, lane = tid & 63, g = lane >> 4, col = lane & 15;
  const short8 Z8 = {0,0,0,0,0,0,0,0};

  for(int ky=0; ky<3; ky++){
    int ys = y + ky - 1;
    const int NCH = 18*CIN/8;
    if(ys < 0 || ys >= HH){
      for(int c8 = tid; c8 < NCH; c8 += 256){
        int px = c8 / (CIN/8), cb = (c8 % (CIN/8))*8;
        *(short8*)&lds[ky][px][cb] = Z8;
      }
    } else {
      size_t base0 = (size_t)(b*HH + ys)*WW*SPLIT;
      size_t base1 = (size_t)(b*HH + ys)*WW*(CIN-SPLIT);
      for(int c8 = tid; c8 < NCH; c8 += 256){
        int px = c8 / (CIN/8), cb = (c8 % (CIN/8))*8;
        int x = pt*16 + px - 1;
        short8 val;
        if(x < 0 || x >= WW){
          val = Z8;
        } else if(cb < SPLIT){
          val = *(const short8*)&in0[base0 + (size_t)x*SPLIT + cb];
        } else if constexpr (IN1F){
          const float* sp = &in1f[base1 + (size_t)x*(CIN-SPLIT) + cb - SPLIT];
          #pragma unroll
          for(int j=0;j<8;j++) val[j] = (short)f2bf(sp[j]);
        } else {
          val = *(const short8*)&in1b[base1 + (size_t)x*(CIN-SPLIT) + cb - SPLIT];
        }
        *(short8*)&lds[ky][px][cb] = val;
      }
    }
  }
  __syncthreads();

  const f32x4 zf = {0.f,0.f,0.f,0.f};
  f32x4 acc[NTW];
  #pragma unroll
  for(int i=0; i<NTW; i++) acc[i] = zf;

  #pragma unroll
  for(int ky=0; ky<3; ky++)
  #pragma unroll
  for(int kx=0; kx<3; kx++)
  #pragma unroll
  for(int ks=0; ks<CIN/32; ks++){
    short8 a = *(const short8*)&lds[ky][col + kx][ks*32 + g*8];
    #pragma unroll
    for(int i=0; i<NTW; i++){
      const u16* wp = Wt + (((((ky*3+kx)*(COUT/16)) + (wave + 4*i))*(CIN/32) + ks)<<9) + lane*8;
      short8 bfr = *(const short8*)wp;
      acc[i] = mfma16(a, bfr, acc[i]);
    }
  }

  if constexpr (!GATE){
    u16* out0 = (u16*)out0v;
    #pragma unroll
    for(int i=0; i<NTW; i++){
      int co = (wave + 4*i)*16 + col;
      float bs = bias[co];
      u16* op = out0 + (size_t)(b*HH + y)*WW*COUT + co;
      #pragma unroll
      for(int r=0; r<4; r++){
        int px = pt*16 + g*4 + r;
        op[(size_t)px*COUT] = f2bf(acc[i][r] + bs);
      }
    }
  } else {
    float* oh = (float*)out0v;
    float* om = (float*)out1v;
    int c = wave*16 + col;
    float bo = bias[c], bg = bias[64+c], bgi = bias[128+c];
    #pragma unroll
    for(int r=0; r<4; r++){
      int px = pt*16 + g*4 + r;
      size_t idx = ((size_t)(b*HH + y)*WW + px)*64 + c;
      float mo = acc[0][r] + bo;
      float mg = acc[1][r] + bg;
      float gi = acc[2][r] + bgi;
      float mval = mem[idx];
      float si = 1.f/(1.f + __expf(-gi));
      float nm = (1.f - si)*mval + si*tanhf(mg);
      float nh = (1.f/(1.f + __expf(-mo)))*nm;
      oh[idx] = nh;
      om[idx] = nm;
    }
  }
}

// ---------------- launcher ----------------
extern "C" void kernel_launch(void* const* d_in, const int* in_sizes, int n_in,
                              void* d_out, int out_size, void* d_ws, size_t ws_size,
                              hipStream_t stream){
  (void)in_sizes; (void)n_in; (void)out_size; (void)ws_size;
  const float* h   = (const float*)d_in[0];
  const float* m   = (const float*)d_in[1];
  const float* Wq  = (const float*)d_in[2];  const float* bq  = (const float*)d_in[3];
  const float* Wk  = (const float*)d_in[4];  const float* bk  = (const float*)d_in[5];
  const float* Wk2 = (const float*)d_in[6];  const float* bk2 = (const float*)d_in[7];
  const float* Wv  = (const float*)d_in[8];  const float* bv  = (const float*)d_in[9];
  const float* Wv2 = (const float*)d_in[10]; const float* bv2 = (const float*)d_in[11];
  const float* Wz  = (const float*)d_in[12]; const float* bz  = (const float*)d_in[13];
  const float* Wm  = (const float*)d_in[14]; const float* bm  = (const float*)d_in[15];

  const size_t NPIX = (size_t)BB*NSEQ*DD;  // 1,179,648

  u16* ws = (u16*)d_ws;
  u16* WtQ  = ws + 0;            // all 7 packed weights contiguous: 663552 u16
  u16* WtK  = ws + 36864;
  u16* WtK2 = ws + 73728;
  u16* WtV  = ws + 110592;
  u16* WtV2 = ws + 147456;
  u16* WtZ  = ws + 184320;
  u16* WtM  = ws + 331776;
  u16* slotA = ws + 663552;      // q;   later Z low half
  u16* slotB = slotA + NPIX;     // k_h; later Z high half
  u16* slotC = slotB + NPIX;     // v_h^T [b][d][seq]
  u16* slotD = slotC + NPIX;     // k_m
  u16* slotE = slotD + NPIX;     // v_m^T [b][d][seq]
  u16* pox   = slotE + NPIX;     // partial regions 4..5 (2 NPIX)
  float2* ml = (float2*)(pox + 2*NPIX);   // 6*BB*NSEQ float2; total ws 18.7 MB
  u16* Zb    = slotA;            // 2*NPIX spanning A+B

  float* outh = (float*)d_out;   // final new_h (f32)
  float* outm = outh + NPIX;     // final new_m (f32)
  u16* po = (u16*)d_out;         // partial regions 0..3 (4 NPIX u16)
  u16* zh = po;                  // after combine: z_h
  u16* zm = po + NPIX;           // after combine: z_m

  WtSrcs wsrc;
  wsrc.src[0]=Wq; wsrc.src[1]=Wk; wsrc.src[2]=Wk2; wsrc.src[3]=Wv; wsrc.src[4]=Wv2;
  wsrc.src[5]=Wz; wsrc.src[6]=Wm;
  wtrans_all<<<dim3(2592), 256, 0, stream>>>(wsrc, ws);

  ConvPtrs ph;
  ph.W[0]=WtQ;  ph.W[1]=WtK;  ph.W[2]=WtV;
  ph.bias[0]=bq; ph.bias[1]=bk; ph.bias[2]=bv;
  ph.out[0]=slotA; ph.out[1]=slotB; ph.out[2]=slotC;
  ph.vt[0]=0; ph.vt[1]=0; ph.vt[2]=1;
  ph.nc = 3;

  ConvPtrs pm;
  pm.W[0]=WtK2; pm.W[1]=WtV2; pm.W[2]=WtV2;
  pm.bias[0]=bk2; pm.bias[1]=bv2; pm.bias[2]=bv2;
  pm.out[0]=slotD; pm.out[1]=slotE; pm.out[2]=slotE;
  pm.vt[0]=0; pm.vt[1]=1; pm.vt[2]=1;
  pm.nc = 2;

  // both conv64 streams in one dispatch (z: 0=h, 1=m)
  conv64_mfma<<<dim3(BB*HH, 1, 2), 256, 0, stream>>>(h, m, ph, pm);

  // stream-split + 3-way split-K attention -> partials (d_out + ws) + l in ws
  attn2_mfma<<<dim3(NSEQ/64, BB, 6), 256, 0, stream>>>(
      slotA, slotB, slotC, slotD, slotE, po, pox, ml);

  // combine chunk triples -> z_h, z_m (in d_out)
  attn_combine<<<dim3(2048), 256, 0, stream>>>(po, pox, ml);

  // Z = conv(concat(z_h, z_m)) -> bf16 into Zb; pixel-tiled + packed weights
  bigconv_mfma<128,128,64,false,false><<<dim3(BB*HH, 1, 3), 256, 0, stream>>>(
      zh, zm, (const float*)0, WtZ, bz, (void*)Zb, (void*)0, (const float*)0);

  // combined = conv(concat(Z, h)); fused gating -> f32 outputs; pixel-tiled
  bigconv_mfma<192,192,128,true,true><<<dim3(BB*HH, 1, 3), 256, 0, stream>>>(
      Zb, (const u16*)0, h, WtM, bm, (void*)outh, (void*)outm, m);
}